// Round 8
// baseline (1852.106 us; speedup 1.0000x reference)
//
#include <hip/hip_runtime.h>
#include <hip/hip_bf16.h>

// ---------------------------------------------------------------------------
// ResidualAttentionBlock (space-time ViT block), MI355X — MFMA bf16, low-ws.
// Peak workspace ~197 MiB (n-chunked attention, no x2 materialization,
// bf16 residual terms, sliced MLP hidden).
// ---------------------------------------------------------------------------

#define DEV static __device__ __forceinline__

constexpr int D     = 768;
constexpr int TT    = 8;
constexpr int BT    = 128;
constexpr int NTOK  = 197;
constexpr int NTOK2 = 198;
constexpr int NKV   = 394;
constexpr int NKVP  = 448;   // padded kv (7*64)
constexpr int NQP   = 224;   // padded q (7*32)
constexpr int NSZ   = 64;    // n-chunk size (2 chunks)
constexpr int MQ    = NTOK2 * NSZ;   // 12672 rows per chunk (Q gemm)
constexpr int MKV   = NKV   * NSZ;   // 25216 rows per chunk (K/V gemm)

constexpr int R2 = NTOK2 * BT;   // 25344
constexpr int R3 = NTOK  * BT;   // 25216

// ---- workspace layout (units: floats); total 51,659,776 fl ~= 197 MiB ----
constexpr size_t O_WB  = 0;                      // bf16 weights (7,962,624 us)
constexpr size_t O_XLN = 3981312;                // xln bf16 R2*768 -> ao2b
constexpr size_t O_AO  = O_XLN + 9732096;        // AO bf16 R2*768 -> xn
constexpr size_t O_QT  = O_AO  + 9732096;        // Qt chunk -> h192 -> h19m
constexpr size_t O_KT  = O_QT  + 5505024;        // Kt chunk -> sadb
constexpr size_t O_VT  = O_KT  + 11010048;       // Vt chunk -> hfcb
constexpr size_t O_SM  = O_VT  + 11010048;
constexpr size_t O_XT   = O_SM;                  // f32 128*768
constexpr size_t O_XTN  = O_XT  + 98304;         // bf16 128*768
constexpr size_t O_QKVT = O_XTN + 49152;         // f32 128*2304
constexpr size_t O_AT   = O_QKVT+ 294912;        // bf16 128*768
constexpr size_t O_ATP  = O_AT  + 49152;         // bf16 128*768
constexpr size_t O_TH   = O_ATP + 49152;         // bf16 128*192
constexpr size_t O_XT2  = O_TH  + 12288;         // f32 128*768
constexpr size_t O_MQ   = O_XT2 + 98304;         // int MQ
constexpr size_t O_MKV  = O_MQ  + 12672;         // int MKV

// bf16 weight offsets (ushort units) within O_WB
constexpr size_t WB_INW = 0;         // 2304*768
constexpr size_t WB_OUTW= 1769472;   // 768*768
constexpr size_t WB_FCW = 2359296;   // 3072*768
constexpr size_t WB_PJW = 4718592;   // 768*3072
constexpr size_t WB_T1W = 7077888;   // 192*768
constexpr size_t WB_T2W = 7225344;   // 768*192
constexpr size_t WB_S1W = 7372800;
constexpr size_t WB_S2W = 7520256;
constexpr size_t WB_M1W = 7667712;
constexpr size_t WB_M2W = 7815168;

typedef __attribute__((ext_vector_type(8))) short bf16x8;
typedef __attribute__((ext_vector_type(4))) float f32x4;
#define MFMA16 __builtin_amdgcn_mfma_f32_16x16x32_bf16

DEV float bf2f(unsigned short u) { return __uint_as_float(((unsigned)u) << 16); }
DEV unsigned short f2bf(float f) {
    unsigned u = __float_as_uint(f);
    u += 0x7fffu + ((u >> 16) & 1u);
    return (unsigned short)(u >> 16);
}

// ---------------------------------------------------------------------------
__global__ __launch_bounds__(256) void convert_k(const float* __restrict__ src,
                                                 unsigned short* __restrict__ dst, int n)
{
    int i = blockIdx.x * 256 + threadIdx.x;
    if (i < n) dst[i] = f2bf(src[i]);
}

// ---------------------------------------------------------------------------
// MFMA GEMM: Y[M,N] = act(A_bf16[M,K] @ W_bf16[N,:K (stride wlda)]^T + bscale*bias)
// tile 128x64, 256 threads (4 waves). grid (N/64, M/128). M%128==0,N%64==0,K%32==0.
// EPI: 0 none, 1 exact GELU, 2 quickGELU
// OMODE: 0 f32  1 bf16  3 Kt-chunk  4 Vt-chunk  5 Qt-chunk(*0.125)  6 f32+=  7 f32+=0.5*
// chunk epilogues (3/4/5): j=rowg>>6 (token), bbl=rowg&63 (chunk-local n)
// ---------------------------------------------------------------------------
template<int EPI, int OMODE>
__global__ __launch_bounds__(256) void gemm_mfma_k(
    const unsigned short* __restrict__ A, const int* __restrict__ rowmap,
    const unsigned short* __restrict__ Wb, int wlda,
    const float* __restrict__ bias, float bscale,
    float* __restrict__ Yf, unsigned short* __restrict__ Yb, int N, int K)
{
    __shared__ unsigned short Als[128][40];
    __shared__ unsigned short Wls[64][40];
    const int tid = threadIdx.x;
    const int n0 = blockIdx.x * 64, m0 = blockIdx.y * 128;
    const int w = tid >> 6, l = tid & 63;

    const int sr = tid >> 2, sseg = tid & 3;
    int gr1 = m0 + sr, gr2 = m0 + 64 + sr;
    if (rowmap) { gr1 = rowmap[gr1]; gr2 = rowmap[gr2]; }
    const unsigned short* Ap1 = A + (size_t)gr1 * K + sseg * 8;
    const unsigned short* Ap2 = A + (size_t)gr2 * K + sseg * 8;
    const unsigned short* Wp  = Wb + (size_t)(n0 + sr) * wlda + sseg * 8;

    f32x4 acc[2][4];
    #pragma unroll
    for (int r = 0; r < 2; ++r)
        #pragma unroll
        for (int c = 0; c < 4; ++c)
            acc[r][c] = (f32x4){0.f, 0.f, 0.f, 0.f};

    for (int k0 = 0; k0 < K; k0 += 32) {
        __syncthreads();
        *(uint4*)&Als[sr][sseg * 8]      = *(const uint4*)(Ap1 + k0);
        *(uint4*)&Als[64 + sr][sseg * 8] = *(const uint4*)(Ap2 + k0);
        *(uint4*)&Wls[sr][sseg * 8]      = *(const uint4*)(Wp  + k0);
        __syncthreads();

        bf16x8 af[2], bfr[4];
        #pragma unroll
        for (int r = 0; r < 2; ++r)
            af[r] = *(const bf16x8*)&Als[w * 32 + r * 16 + (l & 15)][(l >> 4) * 8];
        #pragma unroll
        for (int c = 0; c < 4; ++c)
            bfr[c] = *(const bf16x8*)&Wls[c * 16 + (l & 15)][(l >> 4) * 8];
        #pragma unroll
        for (int r = 0; r < 2; ++r)
            #pragma unroll
            for (int c = 0; c < 4; ++c)
                acc[r][c] = MFMA16(af[r], bfr[c], acc[r][c], 0, 0, 0);
    }

    #pragma unroll
    for (int r = 0; r < 2; ++r) {
        #pragma unroll
        for (int c = 0; c < 4; ++c) {
            const int colg = n0 + c * 16 + (l & 15);
            const float bv = bscale * bias[colg];
            #pragma unroll
            for (int i = 0; i < 4; ++i) {
                const int rowg = m0 + w * 32 + r * 16 + ((l >> 4) << 2) + i;
                float v = acc[r][c][i] + bv;
                if (EPI == 1) v = 0.5f * v * (1.f + erff(v * 0.70710678118654752f));
                else if (EPI == 2) v = v / (1.f + __expf(-1.702f * v));
                if (OMODE == 0) {
                    Yf[(size_t)rowg * N + colg] = v;
                } else if (OMODE == 1) {
                    Yb[(size_t)rowg * N + colg] = f2bf(v);
                } else if (OMODE == 3) {
                    int j = rowg >> 6, bbl = rowg & 63, h = colg >> 6, d = colg & 63;
                    Yb[(((size_t)bbl * 12 + h) * NKVP + j) * 64 + d] = f2bf(v);
                } else if (OMODE == 4) {
                    int j = rowg >> 6, bbl = rowg & 63, h = colg >> 6, d = colg & 63;
                    Yb[(((size_t)bbl * 12 + h) * 64 + d) * NKVP + j] = f2bf(v);
                } else if (OMODE == 5) {
                    int j = rowg >> 6, bbl = rowg & 63, h = colg >> 6, d = colg & 63;
                    Yb[(((size_t)bbl * 12 + h) * NQP + j) * 64 + d] = f2bf(v * 0.125f);
                } else if (OMODE == 6) {
                    Yf[(size_t)rowg * N + colg] += v;
                } else if (OMODE == 7) {
                    Yf[(size_t)rowg * N + colg] += 0.5f * v;
                }
            }
        }
    }
}

// ---------------------------------------------------------------------------
// LayerNorm, one wave per 768-elem row
// ---------------------------------------------------------------------------
template<typename TO>
__global__ __launch_bounds__(256) void ln_k(
    const float* __restrict__ in, TO* __restrict__ out,
    const float* __restrict__ g, const float* __restrict__ b, int rows)
{
    int w = (int)((blockIdx.x * 256 + threadIdx.x) >> 6);
    int lane = threadIdx.x & 63;
    if (w >= rows) return;
    const float* x = in + (size_t)w * D;
    float v[12];
    float s = 0.f;
    #pragma unroll
    for (int i = 0; i < 12; ++i) { v[i] = x[lane + 64 * i]; s += v[i]; }
    #pragma unroll
    for (int m = 32; m; m >>= 1) s += __shfl_xor(s, m);
    float mean = s * (1.f / 768.f);
    float s2 = 0.f;
    #pragma unroll
    for (int i = 0; i < 12; ++i) { float d0 = v[i] - mean; s2 += d0 * d0; }
    #pragma unroll
    for (int m = 32; m; m >>= 1) s2 += __shfl_xor(s2, m);
    float rstd = rsqrtf(s2 * (1.f / 768.f) + 1e-5f);
    TO* o = out + (size_t)w * D;
    #pragma unroll
    for (int i = 0; i < 12; ++i) {
        int c = lane + 64 * i;
        float y = (v[i] - mean) * rstd * g[c] + b[c];
        if constexpr (sizeof(TO) == 2) o[c] = f2bf(y); else o[c] = y;
    }
}

// ---------------------------------------------------------------------------
// LN1 with fused x2-gather: row r2 = tok*128+bb sources x / xt2 (no x2 buffer)
// ---------------------------------------------------------------------------
__global__ __launch_bounds__(256) void ln_gather_k(
    const float* __restrict__ x, const float* __restrict__ xt2,
    unsigned short* __restrict__ out,
    const float* __restrict__ g, const float* __restrict__ b)
{
    int w = (int)((blockIdx.x * 256 + threadIdx.x) >> 6);
    int lane = threadIdx.x & 63;
    if (w >= R2) return;
    int tok = w >> 7, bb = w & 127;
    const float* src;
    if (tok == 0)      src = x + (size_t)bb * D;
    else if (tok == 1) src = xt2 + (size_t)((bb & 7) * 16 + (bb >> 3)) * D;
    else               src = x + ((size_t)(tok - 1) * BT + bb) * D;
    float v[12];
    float s = 0.f;
    #pragma unroll
    for (int i = 0; i < 12; ++i) { v[i] = src[lane + 64 * i]; s += v[i]; }
    #pragma unroll
    for (int m = 32; m; m >>= 1) s += __shfl_xor(s, m);
    float mean = s * (1.f / 768.f);
    float s2 = 0.f;
    #pragma unroll
    for (int i = 0; i < 12; ++i) { float d0 = v[i] - mean; s2 += d0 * d0; }
    #pragma unroll
    for (int m = 32; m; m >>= 1) s2 += __shfl_xor(s2, m);
    float rstd = rsqrtf(s2 * (1.f / 768.f) + 1e-5f);
    unsigned short* o = out + (size_t)w * D;
    #pragma unroll
    for (int i = 0; i < 12; ++i) {
        int c = lane + 64 * i;
        o[c] = f2bf((v[i] - mean) * rstd * g[c] + b[c]);
    }
}

// ---------------------------------------------------------------------------
// temporal path small kernels
// ---------------------------------------------------------------------------
__global__ __launch_bounds__(256) void gather_cls_k(const float* __restrict__ x, float* __restrict__ xt)
{
    int idx = blockIdx.x * 256 + threadIdx.x;
    if (idx >= 128 * 768) return;
    int row = idx / 768, c = idx % 768;     // row = t*16 + b
    int t = row >> 4, bsel = row & 15;
    xt[idx] = x[(size_t)(bsel * TT + t) * D + c];
}

__global__ __launch_bounds__(64) void attn_temporal_k(
    const float* __restrict__ QKVt, unsigned short* __restrict__ Ot)
{
    int n = blockIdx.x, h = blockIdx.y;
    int lane = threadIdx.x;
    __shared__ float qs[8][64], ks[8][64], vs[8][64];
    __shared__ float ps[8][9];
    {
        int t = lane >> 3, f8 = lane & 7;
        size_t rb = ((size_t)(t * 16 + n)) * 2304 + h * 64 + f8 * 8;
        *(float4*)&qs[t][f8 * 8]     = *(const float4*)&QKVt[rb];
        *(float4*)&qs[t][f8 * 8 + 4] = *(const float4*)&QKVt[rb + 4];
        *(float4*)&ks[t][f8 * 8]     = *(const float4*)&QKVt[rb + 768];
        *(float4*)&ks[t][f8 * 8 + 4] = *(const float4*)&QKVt[rb + 772];
        *(float4*)&vs[t][f8 * 8]     = *(const float4*)&QKVt[rb + 1536];
        *(float4*)&vs[t][f8 * 8 + 4] = *(const float4*)&QKVt[rb + 1540];
    }
    __syncthreads();
    int qt = lane >> 3, kt = lane & 7;
    float s = 0.f;
    #pragma unroll
    for (int d0 = 0; d0 < 64; ++d0) s += qs[qt][d0] * ks[kt][d0];
    s *= 0.125f;
    float mx = s;
    #pragma unroll
    for (int m = 4; m; m >>= 1) mx = fmaxf(mx, __shfl_xor(mx, m));
    float p = __expf(s - mx), sum = p;
    #pragma unroll
    for (int m = 4; m; m >>= 1) sum += __shfl_xor(sum, m);
    ps[qt][kt] = p / sum;
    __syncthreads();
    int dg = lane & 7;
    float o[8] = {};
    #pragma unroll
    for (int k2 = 0; k2 < 8; ++k2) {
        float pp = ps[qt][k2];
        #pragma unroll
        for (int dd = 0; dd < 8; ++dd) o[dd] += pp * vs[k2][dg * 8 + dd];
    }
    unsigned short* op = &Ot[((size_t)(qt * 16 + n)) * D + h * 64 + dg * 8];
    #pragma unroll
    for (int dd = 0; dd < 8; ++dd) op[dd] = f2bf(o[dd]);
}

// ---------------------------------------------------------------------------
// per-chunk row maps (Q and K/V; patch-shift fused in kv map)
// grid: (MQ+MKV)/256 = 148 blocks
// ---------------------------------------------------------------------------
__global__ __launch_bounds__(256) void build_maps_k(int* __restrict__ mq,
                                                    int* __restrict__ mkv, int nbase)
{
    int idx = blockIdx.x * 256 + threadIdx.x;
    if (idx < MQ) {
        int j = idx >> 6, bbl = idx & 63;
        mq[idx] = j * BT + nbase + bbl;
    }
    int k = idx - MQ;
    if (k >= 0 && k < MKV) {
        int j = k >> 6, bb = nbase + (k & 63);
        int src;
        if (j < NTOK2) src = j * BT + bb;
        else {
            const int stab[9] = {-4, 1, 2, -1, 0, 3, -2, -3, 4};
            int p = j - NTOK2, r = p / 14, c = p % 14;
            int s = stab[(r % 3) * 3 + (c % 3)];
            int b = bb >> 3, t = bb & 7;
            int t2 = (t - s) & 7;
            src = (2 + p) * BT + b * TT + t2;
        }
        mkv[k] = src;
    }
}

// ---------------------------------------------------------------------------
// main attention (MFMA, flash online-softmax), one n-chunk of 64.
// grid (7 qtiles, 12 h, 64 nloc), 256 threads = 4 waves.
// Qt [nloc][h][224][64] (pre-scaled), Kt [nloc][h][448][64], Vt [nloc][h][64][448]
// ---------------------------------------------------------------------------
__global__ __launch_bounds__(256) void attn_mfma_k(
    const unsigned short* __restrict__ Qt, const unsigned short* __restrict__ Kt,
    const unsigned short* __restrict__ Vt, unsigned short* __restrict__ AO, int nbase)
{
    const int qt0 = blockIdx.x * 32;
    const int h = blockIdx.y, nloc = blockIdx.z;
    const int tid = threadIdx.x, w = tid >> 6, l = tid & 63;
    __shared__ float Sls[32][68];
    __shared__ unsigned short Pls[32][72];
    __shared__ float mrun[32], lrun[32], alphals[32];

    const size_t baseQ = ((size_t)(nloc * 12 + h)) * NQP * 64;
    const size_t baseK = ((size_t)(nloc * 12 + h)) * NKVP * 64;
    const size_t baseV = ((size_t)(nloc * 12 + h)) * 64 * NKVP;

    bf16x8 qf[2][2];
    #pragma unroll
    for (int qb = 0; qb < 2; ++qb)
        #pragma unroll
        for (int ds = 0; ds < 2; ++ds)
            qf[qb][ds] = *(const bf16x8*)&Qt[baseQ + (size_t)(qt0 + qb * 16 + (l & 15)) * 64 + ds * 32 + (l >> 4) * 8];

    if (tid < 32) { mrun[tid] = -3e30f; lrun[tid] = 0.f; }
    f32x4 of[2];
    of[0] = (f32x4){0.f, 0.f, 0.f, 0.f};
    of[1] = (f32x4){0.f, 0.f, 0.f, 0.f};
    __syncthreads();

    for (int kv0 = 0; kv0 < NKV; kv0 += 64) {
        // ---- S = Q K^T ----
        f32x4 sa[2];
        sa[0] = (f32x4){0.f, 0.f, 0.f, 0.f};
        sa[1] = (f32x4){0.f, 0.f, 0.f, 0.f};
        #pragma unroll
        for (int ds = 0; ds < 2; ++ds) {
            bf16x8 kf = *(const bf16x8*)&Kt[baseK + (size_t)(kv0 + w * 16 + (l & 15)) * 64 + ds * 32 + (l >> 4) * 8];
            #pragma unroll
            for (int qb = 0; qb < 2; ++qb)
                sa[qb] = MFMA16(qf[qb][ds], kf, sa[qb], 0, 0, 0);
        }
        #pragma unroll
        for (int qb = 0; qb < 2; ++qb)
            #pragma unroll
            for (int i = 0; i < 4; ++i)
                Sls[qb * 16 + ((l >> 4) << 2) + i][w * 16 + (l & 15)] = sa[qb][i];
        __syncthreads();

        // ---- online softmax (thread: row tid>>3, cols (tid&7)*8..+7) ----
        {
            int row = tid >> 3, cg = tid & 7;
            float sv[8], pv[8];
            float mx = -3e30f;
            #pragma unroll
            for (int j = 0; j < 8; ++j) {
                int c = cg * 8 + j;
                float s = (kv0 + c < NKV) ? Sls[row][c] : -3e30f;
                sv[j] = s; mx = fmaxf(mx, s);
            }
            mx = fmaxf(mx, __shfl_xor(mx, 1));
            mx = fmaxf(mx, __shfl_xor(mx, 2));
            mx = fmaxf(mx, __shfl_xor(mx, 4));
            float mold = mrun[row];
            float mnew = fmaxf(mold, mx);
            float ps = 0.f;
            #pragma unroll
            for (int j = 0; j < 8; ++j) { float p = __expf(sv[j] - mnew); pv[j] = p; ps += p; }
            ps += __shfl_xor(ps, 1);
            ps += __shfl_xor(ps, 2);
            ps += __shfl_xor(ps, 4);
            if (cg == 0) {
                float al = __expf(mold - mnew);
                alphals[row] = al;
                mrun[row] = mnew;
                lrun[row] = lrun[row] * al + ps;
            }
            #pragma unroll
            for (int j = 0; j < 8; ++j) Pls[row][cg * 8 + j] = f2bf(pv[j]);
        }
        __syncthreads();

        // ---- O = O*alpha + P V ----
        #pragma unroll
        for (int qb = 0; qb < 2; ++qb) {
            #pragma unroll
            for (int i = 0; i < 4; ++i)
                of[qb][i] *= alphals[qb * 16 + ((l >> 4) << 2) + i];
        }
        #pragma unroll
        for (int ks = 0; ks < 2; ++ks) {
            bf16x8 vf = *(const bf16x8*)&Vt[baseV + (size_t)(w * 16 + (l & 15)) * NKVP + kv0 + ks * 32 + (l >> 4) * 8];
            #pragma unroll
            for (int qb = 0; qb < 2; ++qb) {
                bf16x8 pf = *(const bf16x8*)&Pls[qb * 16 + (l & 15)][ks * 32 + (l >> 4) * 8];
                of[qb] = MFMA16(pf, vf, of[qb], 0, 0, 0);
            }
        }
        __syncthreads();
    }

    // ---- store O ----
    #pragma unroll
    for (int qb = 0; qb < 2; ++qb) {
        #pragma unroll
        for (int i = 0; i < 4; ++i) {
            int qrow = qb * 16 + ((l >> 4) << 2) + i;
            int q = qt0 + qrow;
            if (q < NTOK2) {
                float inv = 1.f / lrun[qrow];
                AO[((size_t)q * BT + nbase + nloc) * D + h * 64 + w * 16 + (l & 15)] = f2bf(of[qb][i] * inv);
            }
        }
    }
}

// out = x + ao2b + sadb (bf16 terms), temporal token (index 1) dropped
__global__ __launch_bounds__(256) void residual_drop_k(
    const float* __restrict__ x, const unsigned short* __restrict__ ao2b,
    const unsigned short* __restrict__ sadb, float* __restrict__ out)
{
    int idx = blockIdx.x * 256 + threadIdx.x;    // < R3*D exactly
    int tok = idx / (BT * D), rest = idx % (BT * D);
    int stok = tok ? tok + 1 : 0;
    size_t s = (size_t)stok * BT * D + rest;
    size_t sx = (stok == 0) ? (size_t)rest : (size_t)(stok - 1) * BT * D + rest;
    out[idx] = x[sx] + bf2f(ao2b[s]) + bf2f(sadb[s]);
}

// ---------------------------------------------------------------------------
extern "C" void kernel_launch(void* const* d_in, const int* in_sizes, int n_in,
                              void* d_out, int out_size, void* d_ws, size_t ws_size,
                              hipStream_t stream)
{
    const float* x    = (const float*)d_in[0];
    const float* in_w = (const float*)d_in[1];
    const float* in_b = (const float*)d_in[2];
    const float* outw = (const float*)d_in[3];
    const float* outb = (const float*)d_in[4];
    const float* ln1g = (const float*)d_in[5];
    const float* ln1b = (const float*)d_in[6];
    const float* ln2g = (const float*)d_in[7];
    const float* ln2b = (const float*)d_in[8];
    const float* fcw  = (const float*)d_in[9];
    const float* fcb  = (const float*)d_in[10];
    const float* pjw  = (const float*)d_in[11];
    const float* pjb  = (const float*)d_in[12];
    const float* t1w  = (const float*)d_in[13];
    const float* t1b  = (const float*)d_in[14];
    const float* t2w  = (const float*)d_in[15];
    const float* t2b  = (const float*)d_in[16];
    const float* s1w  = (const float*)d_in[17];
    const float* s1b  = (const float*)d_in[18];
    const float* s2w  = (const float*)d_in[19];
    const float* s2b  = (const float*)d_in[20];
    const float* m1w  = (const float*)d_in[21];
    const float* m1b  = (const float*)d_in[22];
    const float* m2w  = (const float*)d_in[23];
    const float* m2b  = (const float*)d_in[24];

    float* ws  = (float*)d_ws;
    float* out = (float*)d_out;

    unsigned short* WB = (unsigned short*)(ws + O_WB);
    unsigned short* w_in  = WB + WB_INW;
    unsigned short* w_out = WB + WB_OUTW;
    unsigned short* w_fc  = WB + WB_FCW;
    unsigned short* w_pj  = WB + WB_PJW;
    unsigned short* w_t1  = WB + WB_T1W;
    unsigned short* w_t2  = WB + WB_T2W;
    unsigned short* w_s1  = WB + WB_S1W;
    unsigned short* w_s2  = WB + WB_S2W;
    unsigned short* w_m1  = WB + WB_M1W;
    unsigned short* w_m2  = WB + WB_M2W;

    unsigned short* xln  = (unsigned short*)(ws + O_XLN);
    unsigned short* AO   = (unsigned short*)(ws + O_AO);
    unsigned short* Qt   = (unsigned short*)(ws + O_QT);
    unsigned short* Kt   = (unsigned short*)(ws + O_KT);
    unsigned short* Vt   = (unsigned short*)(ws + O_VT);
    unsigned short* ao2b = xln;                             // xln dead after chunk-2 KV
    unsigned short* xn   = AO;                              // AO dead after out-proj
    unsigned short* h192 = Qt;                              // Qt dead after attention
    unsigned short* h19m = Qt;                              // h192 dead after s2
    unsigned short* sadb = Kt;                              // Kt dead after attention
    unsigned short* hfcb = Vt;                              // Vt dead after attention

    float* xt            = ws + O_XT;
    unsigned short* xtn  = (unsigned short*)(ws + O_XTN);
    float* qkvt          = ws + O_QKVT;
    unsigned short* at   = (unsigned short*)(ws + O_AT);
    unsigned short* atp  = (unsigned short*)(ws + O_ATP);
    unsigned short* th   = (unsigned short*)(ws + O_TH);
    float* xt2           = ws + O_XT2;
    int*   mapq          = (int*)(ws + O_MQ);
    int*   mapkv         = (int*)(ws + O_MKV);

    // ---- weight conversion (every launch; ws is re-poisoned) ----
    auto conv = [&](const float* s, unsigned short* dst, int n) {
        convert_k<<<(n + 255) / 256, 256, 0, stream>>>(s, dst, n);
    };
    conv(in_w, w_in, 2304 * 768);
    conv(outw, w_out, 768 * 768);
    conv(fcw,  w_fc,  3072 * 768);
    conv(pjw,  w_pj,  768 * 3072);
    conv(t1w,  w_t1,  192 * 768);
    conv(t2w,  w_t2,  768 * 192);
    conv(s1w,  w_s1,  192 * 768);
    conv(s2w,  w_s2,  768 * 192);
    conv(m1w,  w_m1,  192 * 768);
    conv(m2w,  w_m2,  768 * 192);

    // ---- temporal path ----
    gather_cls_k<<<384, 256, 0, stream>>>(x, xt);
    ln_k<unsigned short><<<32, 256, 0, stream>>>(xt, xtn, ln1g, ln1b, 128);
    gemm_mfma_k<0,0><<<dim3(36,1), 256, 0, stream>>>(xtn, nullptr, w_in, 768, in_b, 1.f, qkvt, nullptr, 2304, 768);
    attn_temporal_k<<<dim3(16,12), 64, 0, stream>>>(qkvt, at);
    gemm_mfma_k<0,1><<<dim3(12,1), 256, 0, stream>>>(at,  nullptr, w_out, 768, outb, 1.f, nullptr, atp, 768, 768);
    gemm_mfma_k<1,1><<<dim3(3,1),  256, 0, stream>>>(atp, nullptr, w_t1,  768, t1b, 1.f, nullptr, th,  192, 768);
    gemm_mfma_k<0,0><<<dim3(12,1), 256, 0, stream>>>(th,  nullptr, w_t2,  192, t2b, 1.f, xt2, nullptr, 768, 192);

    // ---- LN1 with fused x2-gather ----
    ln_gather_k<<<6336, 256, 0, stream>>>(x, xt2, xln, ln1g, ln1b);

    // ---- QKV + attention, 2 n-chunks of 64 ----
    for (int c = 0; c < 2; ++c) {
        const int nbase = c * NSZ;
        build_maps_k<<<148, 256, 0, stream>>>(mapq, mapkv, nbase);
        gemm_mfma_k<0,5><<<dim3(12,99),  256, 0, stream>>>(xln, mapq,  w_in,              768, in_b,        1.f, nullptr, Qt, 768, 768);
        gemm_mfma_k<0,3><<<dim3(12,197), 256, 0, stream>>>(xln, mapkv, w_in + 768 * 768,  768, in_b + 768,  1.f, nullptr, Kt, 768, 768);
        gemm_mfma_k<0,4><<<dim3(12,197), 256, 0, stream>>>(xln, mapkv, w_in + 1536 * 768, 768, in_b + 1536, 1.f, nullptr, Vt, 768, 768);
        attn_mfma_k<<<dim3(7,12,64), 256, 0, stream>>>(Qt, Kt, Vt, AO, nbase);
    }

    // ---- out-proj (bf16) + s-adapter + residual/token-drop ----
    gemm_mfma_k<0,1><<<dim3(12,198), 256, 0, stream>>>(AO,   nullptr, w_out, 768, outb, 1.f, nullptr, ao2b, 768, 768);
    gemm_mfma_k<1,1><<<dim3(3,198),  256, 0, stream>>>(ao2b, nullptr, w_s1,  768, s1b,  1.f, nullptr, h192, 192, 768);
    gemm_mfma_k<0,1><<<dim3(12,198), 256, 0, stream>>>(h192, nullptr, w_s2,  192, s2b,  1.f, nullptr, sadb, 768, 192);
    residual_drop_k<<<75648, 256, 0, stream>>>(x, ao2b, sadb, out);

    // ---- LN2 + m-adapter (fused 0.5x accumulate) ----
    ln_k<unsigned short><<<6304, 256, 0, stream>>>(out, xn, ln2g, ln2b, R3);
    gemm_mfma_k<1,1><<<dim3(3,197),  256, 0, stream>>>(xn,   nullptr, w_m1, 768, m1b, 1.f, nullptr, h19m, 192, 768);
    gemm_mfma_k<0,7><<<dim3(12,197), 256, 0, stream>>>(h19m, nullptr, w_m2, 192, m2b, 1.f, out, nullptr, 768, 192);

    // ---- MLP in 4 hidden slices of 768 (quickGELU; bias added on slice 0) ----
    for (int q = 0; q < 4; ++q) {
        gemm_mfma_k<2,1><<<dim3(12,197), 256, 0, stream>>>(xn,   nullptr, w_fc + (size_t)q * 768 * 768, 768,  fcb + q * 768, 1.f, nullptr, hfcb, 768, 768);
        gemm_mfma_k<0,6><<<dim3(12,197), 256, 0, stream>>>(hfcb, nullptr, w_pj + q * 768,               3072, pjb, (q == 0) ? 1.f : 0.f, out, nullptr, 768, 768);
    }
}

// Round 9
// 1669.913 us; speedup vs baseline: 1.1091x; 1.1091x over previous
//
#include <hip/hip_runtime.h>
#include <hip/hip_bf16.h>

// ---------------------------------------------------------------------------
// ResidualAttentionBlock (space-time ViT block), MI355X — MFMA bf16 v2.
// global_load_lds GEMM staging, coalesced V + LDS-transpose in attention,
// M-chunked MLP with concat-K m-adapter fusion, epilogue-fused residual.
// Peak workspace ~197 MiB (same layout as passing round-8 kernel + 768 fl).
// ---------------------------------------------------------------------------

#define DEV static __device__ __forceinline__

constexpr int D     = 768;
constexpr int TT    = 8;
constexpr int BT    = 128;
constexpr int NTOK  = 197;
constexpr int NTOK2 = 198;
constexpr int NKV   = 394;
constexpr int NKVP  = 448;   // padded kv (7*64)
constexpr int NQP   = 224;   // padded q (7*32)
constexpr int NSZ   = 64;    // n-chunk size (2 chunks)
constexpr int MQ    = NTOK2 * NSZ;   // 12672 rows per chunk (Q gemm)
constexpr int MKV   = NKV   * NSZ;   // 25216 rows per chunk (K/V gemm)
constexpr int KCAT  = 3264;  // 3072 (fc hidden) + 192 (m-adapter hidden)

constexpr int R2 = NTOK2 * BT;   // 25344
constexpr int R3 = NTOK  * BT;   // 25216

// ---- workspace layout (units: floats) — identical to passing round-8 ----
constexpr size_t O_WB  = 0;                      // bf16 weights
constexpr size_t O_XLN = 3981312;                // xln bf16 -> ao2b
constexpr size_t O_AO  = O_XLN + 9732096;        // AO bf16 -> xn
constexpr size_t O_QT  = O_AO  + 9732096;        // Qt chunk -> h192 + pjcat
constexpr size_t O_KT  = O_QT  + 5505024;        // Kt chunk -> catbuf (MLP)
constexpr size_t O_VT  = O_KT  + 11010048;       // Vt chunk
constexpr size_t O_SM  = O_VT  + 11010048;
constexpr size_t O_XT   = O_SM;                  // f32 128*768
constexpr size_t O_XTN  = O_XT  + 98304;         // bf16 128*768
constexpr size_t O_QKVT = O_XTN + 49152;         // f32 128*2304
constexpr size_t O_AT   = O_QKVT+ 294912;        // bf16 128*768
constexpr size_t O_ATP  = O_AT  + 49152;         // bf16 128*768
constexpr size_t O_TH   = O_ATP + 49152;         // bf16 128*192
constexpr size_t O_XT2  = O_TH  + 12288;         // f32 128*768
constexpr size_t O_MQ   = O_XT2 + 98304;         // int MQ
constexpr size_t O_MKV  = O_MQ  + 12672;         // int MKV
constexpr size_t O_CB   = O_MKV + 25216;         // f32 768 combined bias

// bf16 weight offsets (ushort units) within O_WB
constexpr size_t WB_INW = 0;         // 2304*768
constexpr size_t WB_OUTW= 1769472;   // 768*768
constexpr size_t WB_FCW = 2359296;   // 3072*768
constexpr size_t WB_T1W = 7077888;   // 192*768  (pjw/m2w slots repurposed: unused)
constexpr size_t WB_T2W = 7225344;   // 768*192
constexpr size_t WB_S1W = 7372800;
constexpr size_t WB_S2W = 7520256;
constexpr size_t WB_M1W = 7667712;

typedef __attribute__((ext_vector_type(8))) short bf16x8;
typedef __attribute__((ext_vector_type(4))) float f32x4;
#define MFMA16 __builtin_amdgcn_mfma_f32_16x16x32_bf16

DEV float bf2f(unsigned short u) { return __uint_as_float(((unsigned)u) << 16); }
DEV unsigned short f2bf(float f) {
    unsigned u = __float_as_uint(f);
    u += 0x7fffu + ((u >> 16) & 1u);
    return (unsigned short)(u >> 16);
}

DEV void gll16(const unsigned short* g, unsigned short* l) {
    __builtin_amdgcn_global_load_lds(
        (const __attribute__((address_space(1))) void*)g,
        (__attribute__((address_space(3))) void*)l, 16, 0, 0);
}

// ---------------------------------------------------------------------------
__global__ __launch_bounds__(256) void convert_k(const float* __restrict__ src,
                                                 unsigned short* __restrict__ dst, int n)
{
    int i = blockIdx.x * 256 + threadIdx.x;
    if (i < n) dst[i] = f2bf(src[i]);
}

// strided 2-D convert with scale (for concat-K weight build)
__global__ __launch_bounds__(256) void convert2d_k(const float* __restrict__ src,
    int rows, int cols, int sld, unsigned short* __restrict__ dst, int dld, float scale)
{
    int i = blockIdx.x * 256 + threadIdx.x;
    if (i >= rows * cols) return;
    int r = i / cols, c = i % cols;
    dst[(size_t)r * dld + c] = f2bf(src[(size_t)r * sld + c] * scale);
}

__global__ __launch_bounds__(256) void combine_bias_k(const float* __restrict__ a,
    const float* __restrict__ b, float* __restrict__ cb)
{
    int i = blockIdx.x * 256 + threadIdx.x;
    if (i < 768) cb[i] = a[i] + 0.5f * b[i];
}

// ---------------------------------------------------------------------------
// MFMA GEMM with global_load_lds staging.
// Y[M,N] = act(A_bf16[M,K(stride K)] @ W_bf16[N,:K (stride wlda)]^T + bscale*bias)
// tile 128x64, 256 threads (4 waves). grid (N/64, M/128). M%128==0,N%64==0,K%32==0.
// EPI: 0 none, 1 exact GELU, 2 quickGELU
// OMODE: 0 f32  1 bf16  3 K/V-chunk scatter  5 Qt-chunk(*0.125)  6 f32 +=
//        8 residual fusion: out[drop(tok)] = X + bf16(Yb) + v
// ---------------------------------------------------------------------------
template<int EPI, int OMODE>
__global__ __launch_bounds__(256) void gemm_mfma_k(
    const unsigned short* __restrict__ A, const int* __restrict__ rowmap,
    const unsigned short* __restrict__ Wb, int wlda,
    const float* __restrict__ bias, float bscale,
    float* __restrict__ Yf, unsigned short* __restrict__ Yb,
    int N, int K, int ldy, const float* __restrict__ Xf)
{
    __shared__ unsigned short Als[128][32];
    __shared__ unsigned short Wls[64][32];
    const int tid = threadIdx.x;
    const int n0 = blockIdx.x * 64, m0 = blockIdx.y * 128;
    const int w = tid >> 6, l = tid & 63;

    // per-wave async staging: wave w loads A rows [w*32, w*32+32), W rows [w*16,+16)
    int ga0 = m0 + w * 32 + (l >> 2);
    int ga1 = ga0 + 16;
    const int gw = n0 + w * 16 + (l >> 2);
    if (rowmap) { ga0 = rowmap[ga0]; ga1 = rowmap[ga1]; }
    const unsigned short* Ap0 = A + (size_t)ga0 * K + (l & 3) * 8;
    const unsigned short* Ap1 = A + (size_t)ga1 * K + (l & 3) * 8;
    const unsigned short* Wp  = Wb + (size_t)gw * wlda + (l & 3) * 8;
    unsigned short* lA0 = &Als[w * 32 + (l >> 2)][(l & 3) * 8];
    unsigned short* lA1 = &Als[w * 32 + 16 + (l >> 2)][(l & 3) * 8];
    unsigned short* lW  = &Wls[w * 16 + (l >> 2)][(l & 3) * 8];

    f32x4 acc[2][4];
    #pragma unroll
    for (int r = 0; r < 2; ++r)
        #pragma unroll
        for (int c = 0; c < 4; ++c)
            acc[r][c] = (f32x4){0.f, 0.f, 0.f, 0.f};

    for (int k0 = 0; k0 < K; k0 += 32) {
        __syncthreads();
        gll16(Ap0 + k0, lA0);
        gll16(Ap1 + k0, lA1);
        gll16(Wp  + k0, lW);
        __syncthreads();   // compiler emits vmcnt(0) before barrier -> data ready

        bf16x8 af[2], bfr[4];
        #pragma unroll
        for (int r = 0; r < 2; ++r)
            af[r] = *(const bf16x8*)&Als[w * 32 + r * 16 + (l & 15)][(l >> 4) * 8];
        #pragma unroll
        for (int c = 0; c < 4; ++c)
            bfr[c] = *(const bf16x8*)&Wls[c * 16 + (l & 15)][(l >> 4) * 8];
        #pragma unroll
        for (int r = 0; r < 2; ++r)
            #pragma unroll
            for (int c = 0; c < 4; ++c)
                acc[r][c] = MFMA16(af[r], bfr[c], acc[r][c], 0, 0, 0);
    }

    #pragma unroll
    for (int r = 0; r < 2; ++r) {
        #pragma unroll
        for (int c = 0; c < 4; ++c) {
            const int colg = n0 + c * 16 + (l & 15);
            const float bv = bscale * bias[colg];
            #pragma unroll
            for (int i = 0; i < 4; ++i) {
                const int rowg = m0 + w * 32 + r * 16 + ((l >> 4) << 2) + i;
                float v = acc[r][c][i] + bv;
                if (EPI == 1) v = 0.5f * v * (1.f + erff(v * 0.70710678118654752f));
                else if (EPI == 2) v = v / (1.f + __expf(-1.702f * v));
                if (OMODE == 0) {
                    Yf[(size_t)rowg * ldy + colg] = v;
                } else if (OMODE == 1) {
                    Yb[(size_t)rowg * ldy + colg] = f2bf(v);
                } else if (OMODE == 3) {
                    int j = rowg >> 6, bbl = rowg & 63, h = colg >> 6, d = colg & 63;
                    Yb[(((size_t)bbl * 12 + h) * NKVP + j) * 64 + d] = f2bf(v);
                } else if (OMODE == 5) {
                    int j = rowg >> 6, bbl = rowg & 63, h = colg >> 6, d = colg & 63;
                    Yb[(((size_t)bbl * 12 + h) * NQP + j) * 64 + d] = f2bf(v * 0.125f);
                } else if (OMODE == 6) {
                    Yf[(size_t)rowg * ldy + colg] += v;
                } else if (OMODE == 8) {
                    int tok2 = rowg >> 7, bb2 = rowg & 127;
                    if (tok2 != 1) {
                        int otok = tok2 ? tok2 - 1 : 0;
                        size_t oi = ((size_t)(otok * BT + bb2)) * ldy + colg;
                        Yf[oi] = Xf[oi] + bf2f(Yb[(size_t)rowg * ldy + colg]) + v;
                    }
                }
            }
        }
    }
}

// ---------------------------------------------------------------------------
// LayerNorm, one wave per 768-elem row
// ---------------------------------------------------------------------------
template<typename TO>
__global__ __launch_bounds__(256) void ln_k(
    const float* __restrict__ in, TO* __restrict__ out,
    const float* __restrict__ g, const float* __restrict__ b, int rows)
{
    int w = (int)((blockIdx.x * 256 + threadIdx.x) >> 6);
    int lane = threadIdx.x & 63;
    if (w >= rows) return;
    const float* x = in + (size_t)w * D;
    float v[12];
    float s = 0.f;
    #pragma unroll
    for (int i = 0; i < 12; ++i) { v[i] = x[lane + 64 * i]; s += v[i]; }
    #pragma unroll
    for (int m = 32; m; m >>= 1) s += __shfl_xor(s, m);
    float mean = s * (1.f / 768.f);
    float s2 = 0.f;
    #pragma unroll
    for (int i = 0; i < 12; ++i) { float d0 = v[i] - mean; s2 += d0 * d0; }
    #pragma unroll
    for (int m = 32; m; m >>= 1) s2 += __shfl_xor(s2, m);
    float rstd = rsqrtf(s2 * (1.f / 768.f) + 1e-5f);
    TO* o = out + (size_t)w * D;
    #pragma unroll
    for (int i = 0; i < 12; ++i) {
        int c = lane + 64 * i;
        float y = (v[i] - mean) * rstd * g[c] + b[c];
        if constexpr (sizeof(TO) == 2) o[c] = f2bf(y); else o[c] = y;
    }
}

// ---------------------------------------------------------------------------
// LN1 with fused x2-gather
// ---------------------------------------------------------------------------
__global__ __launch_bounds__(256) void ln_gather_k(
    const float* __restrict__ x, const float* __restrict__ xt2,
    unsigned short* __restrict__ out,
    const float* __restrict__ g, const float* __restrict__ b)
{
    int w = (int)((blockIdx.x * 256 + threadIdx.x) >> 6);
    int lane = threadIdx.x & 63;
    if (w >= R2) return;
    int tok = w >> 7, bb = w & 127;
    const float* src;
    if (tok == 0)      src = x + (size_t)bb * D;
    else if (tok == 1) src = xt2 + (size_t)((bb & 7) * 16 + (bb >> 3)) * D;
    else               src = x + ((size_t)(tok - 1) * BT + bb) * D;
    float v[12];
    float s = 0.f;
    #pragma unroll
    for (int i = 0; i < 12; ++i) { v[i] = src[lane + 64 * i]; s += v[i]; }
    #pragma unroll
    for (int m = 32; m; m >>= 1) s += __shfl_xor(s, m);
    float mean = s * (1.f / 768.f);
    float s2 = 0.f;
    #pragma unroll
    for (int i = 0; i < 12; ++i) { float d0 = v[i] - mean; s2 += d0 * d0; }
    #pragma unroll
    for (int m = 32; m; m >>= 1) s2 += __shfl_xor(s2, m);
    float rstd = rsqrtf(s2 * (1.f / 768.f) + 1e-5f);
    unsigned short* o = out + (size_t)w * D;
    #pragma unroll
    for (int i = 0; i < 12; ++i) {
        int c = lane + 64 * i;
        o[c] = f2bf((v[i] - mean) * rstd * g[c] + b[c]);
    }
}

// ---------------------------------------------------------------------------
// temporal path small kernels
// ---------------------------------------------------------------------------
__global__ __launch_bounds__(256) void gather_cls_k(const float* __restrict__ x, float* __restrict__ xt)
{
    int idx = blockIdx.x * 256 + threadIdx.x;
    if (idx >= 128 * 768) return;
    int row = idx / 768, c = idx % 768;     // row = t*16 + b
    int t = row >> 4, bsel = row & 15;
    xt[idx] = x[(size_t)(bsel * TT + t) * D + c];
}

__global__ __launch_bounds__(64) void attn_temporal_k(
    const float* __restrict__ QKVt, unsigned short* __restrict__ Ot)
{
    int n = blockIdx.x, h = blockIdx.y;
    int lane = threadIdx.x;
    __shared__ float qs[8][64], ks[8][64], vs[8][64];
    __shared__ float ps[8][9];
    {
        int t = lane >> 3, f8 = lane & 7;
        size_t rb = ((size_t)(t * 16 + n)) * 2304 + h * 64 + f8 * 8;
        *(float4*)&qs[t][f8 * 8]     = *(const float4*)&QKVt[rb];
        *(float4*)&qs[t][f8 * 8 + 4] = *(const float4*)&QKVt[rb + 4];
        *(float4*)&ks[t][f8 * 8]     = *(const float4*)&QKVt[rb + 768];
        *(float4*)&ks[t][f8 * 8 + 4] = *(const float4*)&QKVt[rb + 772];
        *(float4*)&vs[t][f8 * 8]     = *(const float4*)&QKVt[rb + 1536];
        *(float4*)&vs[t][f8 * 8 + 4] = *(const float4*)&QKVt[rb + 1540];
    }
    __syncthreads();
    int qt = lane >> 3, kt = lane & 7;
    float s = 0.f;
    #pragma unroll
    for (int d0 = 0; d0 < 64; ++d0) s += qs[qt][d0] * ks[kt][d0];
    s *= 0.125f;
    float mx = s;
    #pragma unroll
    for (int m = 4; m; m >>= 1) mx = fmaxf(mx, __shfl_xor(mx, m));
    float p = __expf(s - mx), sum = p;
    #pragma unroll
    for (int m = 4; m; m >>= 1) sum += __shfl_xor(sum, m);
    ps[qt][kt] = p / sum;
    __syncthreads();
    int dg = lane & 7;
    float o[8] = {};
    #pragma unroll
    for (int k2 = 0; k2 < 8; ++k2) {
        float pp = ps[qt][k2];
        #pragma unroll
        for (int dd = 0; dd < 8; ++dd) o[dd] += pp * vs[k2][dg * 8 + dd];
    }
    unsigned short* op = &Ot[((size_t)(qt * 16 + n)) * D + h * 64 + dg * 8];
    #pragma unroll
    for (int dd = 0; dd < 8; ++dd) op[dd] = f2bf(o[dd]);
}

// ---------------------------------------------------------------------------
// per-chunk row maps
// ---------------------------------------------------------------------------
__global__ __launch_bounds__(256) void build_maps_k(int* __restrict__ mq,
                                                    int* __restrict__ mkv, int nbase)
{
    int idx = blockIdx.x * 256 + threadIdx.x;
    if (idx < MQ) {
        int j = idx >> 6, bbl = idx & 63;
        mq[idx] = j * BT + nbase + bbl;
    }
    int k = idx - MQ;
    if (k >= 0 && k < MKV) {
        int j = k >> 6, bb = nbase + (k & 63);
        int src;
        if (j < NTOK2) src = j * BT + bb;
        else {
            const int stab[9] = {-4, 1, 2, -1, 0, 3, -2, -3, 4};
            int p = j - NTOK2, r = p / 14, c = p % 14;
            int s = stab[(r % 3) * 3 + (c % 3)];
            int b = bb >> 3, t = bb & 7;
            int t2 = (t - s) & 7;
            src = (2 + p) * BT + b * TT + t2;
        }
        mkv[k] = src;
    }
}

// ---------------------------------------------------------------------------
// main attention (MFMA, flash online-softmax), one n-chunk of 64.
// grid (7 qtiles, 12 h, 64 nloc), 256 threads = 4 waves.
// Qt [nloc][h][224][64] (pre-scaled), Kt/Vt [nloc][h][448][64] — V transposed
// to LDS per 64-kv tile for the PV B-fragment.
// ---------------------------------------------------------------------------
__global__ __launch_bounds__(256) void attn_mfma_k(
    const unsigned short* __restrict__ Qt, const unsigned short* __restrict__ Kt,
    const unsigned short* __restrict__ Vt, unsigned short* __restrict__ AO, int nbase)
{
    const int qt0 = blockIdx.x * 32;
    const int h = blockIdx.y, nloc = blockIdx.z;
    const int tid = threadIdx.x, w = tid >> 6, l = tid & 63;
    __shared__ float Sls[32][68];
    __shared__ unsigned short Pls[32][72];
    __shared__ unsigned short Vls[64][72];   // [d][kv-local]
    __shared__ float mrun[32], lrun[32], alphals[32];

    const size_t baseQ = ((size_t)(nloc * 12 + h)) * NQP * 64;
    const size_t baseK = ((size_t)(nloc * 12 + h)) * NKVP * 64;

    bf16x8 qf[2][2];
    #pragma unroll
    for (int qb = 0; qb < 2; ++qb)
        #pragma unroll
        for (int ds = 0; ds < 2; ++ds)
            qf[qb][ds] = *(const bf16x8*)&Qt[baseQ + (size_t)(qt0 + qb * 16 + (l & 15)) * 64 + ds * 32 + (l >> 4) * 8];

    if (tid < 32) { mrun[tid] = -3e30f; lrun[tid] = 0.f; }
    f32x4 of[2];
    of[0] = (f32x4){0.f, 0.f, 0.f, 0.f};
    of[1] = (f32x4){0.f, 0.f, 0.f, 0.f};
    __syncthreads();

    for (int kv0 = 0; kv0 < NKV; kv0 += 64) {
        // ---- stage V tile (coalesced global read, transposed LDS write) ----
        #pragma unroll
        for (int p = 0; p < 2; ++p) {
            int idx = tid + p * 256;
            int j = idx >> 3, seg = idx & 7;
            uint4 vv = *(const uint4*)&Vt[baseK + (size_t)(kv0 + j) * 64 + seg * 8];
            const unsigned short* pv = (const unsigned short*)&vv;
            #pragma unroll
            for (int e = 0; e < 8; ++e) Vls[seg * 8 + e][j] = pv[e];
        }
        // ---- S = Q K^T ----
        f32x4 sa[2];
        sa[0] = (f32x4){0.f, 0.f, 0.f, 0.f};
        sa[1] = (f32x4){0.f, 0.f, 0.f, 0.f};
        #pragma unroll
        for (int ds = 0; ds < 2; ++ds) {
            bf16x8 kf = *(const bf16x8*)&Kt[baseK + (size_t)(kv0 + w * 16 + (l & 15)) * 64 + ds * 32 + (l >> 4) * 8];
            #pragma unroll
            for (int qb = 0; qb < 2; ++qb)
                sa[qb] = MFMA16(qf[qb][ds], kf, sa[qb], 0, 0, 0);
        }
        #pragma unroll
        for (int qb = 0; qb < 2; ++qb)
            #pragma unroll
            for (int i = 0; i < 4; ++i)
                Sls[qb * 16 + ((l >> 4) << 2) + i][w * 16 + (l & 15)] = sa[qb][i];
        __syncthreads();

        // ---- online softmax ----
        {
            int row = tid >> 3, cg = tid & 7;
            float sv[8], pv[8];
            float mx = -3e30f;
            #pragma unroll
            for (int j = 0; j < 8; ++j) {
                int c = cg * 8 + j;
                float s = (kv0 + c < NKV) ? Sls[row][c] : -3e30f;
                sv[j] = s; mx = fmaxf(mx, s);
            }
            mx = fmaxf(mx, __shfl_xor(mx, 1));
            mx = fmaxf(mx, __shfl_xor(mx, 2));
            mx = fmaxf(mx, __shfl_xor(mx, 4));
            float mold = mrun[row];
            float mnew = fmaxf(mold, mx);
            float ps = 0.f;
            #pragma unroll
            for (int j = 0; j < 8; ++j) { float p = __expf(sv[j] - mnew); pv[j] = p; ps += p; }
            ps += __shfl_xor(ps, 1);
            ps += __shfl_xor(ps, 2);
            ps += __shfl_xor(ps, 4);
            if (cg == 0) {
                float al = __expf(mold - mnew);
                alphals[row] = al;
                mrun[row] = mnew;
                lrun[row] = lrun[row] * al + ps;
            }
            #pragma unroll
            for (int j = 0; j < 8; ++j) Pls[row][cg * 8 + j] = f2bf(pv[j]);
        }
        __syncthreads();

        // ---- O = O*alpha + P V (V from LDS transpose) ----
        #pragma unroll
        for (int qb = 0; qb < 2; ++qb) {
            #pragma unroll
            for (int i = 0; i < 4; ++i)
                of[qb][i] *= alphals[qb * 16 + ((l >> 4) << 2) + i];
        }
        #pragma unroll
        for (int ks = 0; ks < 2; ++ks) {
            bf16x8 vf = *(const bf16x8*)&Vls[w * 16 + (l & 15)][ks * 32 + (l >> 4) * 8];
            #pragma unroll
            for (int qb = 0; qb < 2; ++qb) {
                bf16x8 pf = *(const bf16x8*)&Pls[qb * 16 + (l & 15)][ks * 32 + (l >> 4) * 8];
                of[qb] = MFMA16(pf, vf, of[qb], 0, 0, 0);
            }
        }
        __syncthreads();
    }

    // ---- store O ----
    #pragma unroll
    for (int qb = 0; qb < 2; ++qb) {
        #pragma unroll
        for (int i = 0; i < 4; ++i) {
            int qrow = qb * 16 + ((l >> 4) << 2) + i;
            int q = qt0 + qrow;
            if (q < NTOK2) {
                float inv = 1.f / lrun[qrow];
                AO[((size_t)q * BT + nbase + nloc) * D + h * 64 + w * 16 + (l & 15)] = f2bf(of[qb][i] * inv);
            }
        }
    }
}

// ---------------------------------------------------------------------------
extern "C" void kernel_launch(void* const* d_in, const int* in_sizes, int n_in,
                              void* d_out, int out_size, void* d_ws, size_t ws_size,
                              hipStream_t stream)
{
    const float* x    = (const float*)d_in[0];
    const float* in_w = (const float*)d_in[1];
    const float* in_b = (const float*)d_in[2];
    const float* outw = (const float*)d_in[3];
    const float* outb = (const float*)d_in[4];
    const float* ln1g = (const float*)d_in[5];
    const float* ln1b = (const float*)d_in[6];
    const float* ln2g = (const float*)d_in[7];
    const float* ln2b = (const float*)d_in[8];
    const float* fcw  = (const float*)d_in[9];
    const float* fcb  = (const float*)d_in[10];
    const float* pjw  = (const float*)d_in[11];
    const float* pjb  = (const float*)d_in[12];
    const float* t1w  = (const float*)d_in[13];
    const float* t1b  = (const float*)d_in[14];
    const float* t2w  = (const float*)d_in[15];
    const float* t2b  = (const float*)d_in[16];
    const float* s1w  = (const float*)d_in[17];
    const float* s1b  = (const float*)d_in[18];
    const float* s2w  = (const float*)d_in[19];
    const float* s2b  = (const float*)d_in[20];
    const float* m1w  = (const float*)d_in[21];
    const float* m1b  = (const float*)d_in[22];
    const float* m2w  = (const float*)d_in[23];
    const float* m2b  = (const float*)d_in[24];

    float* ws  = (float*)d_ws;
    float* out = (float*)d_out;

    unsigned short* WB = (unsigned short*)(ws + O_WB);
    unsigned short* w_in  = WB + WB_INW;
    unsigned short* w_out = WB + WB_OUTW;
    unsigned short* w_fc  = WB + WB_FCW;
    unsigned short* w_t1  = WB + WB_T1W;
    unsigned short* w_t2  = WB + WB_T2W;
    unsigned short* w_s1  = WB + WB_S1W;
    unsigned short* w_s2  = WB + WB_S2W;
    unsigned short* w_m1  = WB + WB_M1W;

    unsigned short* xln  = (unsigned short*)(ws + O_XLN);
    unsigned short* AO   = (unsigned short*)(ws + O_AO);
    unsigned short* Qt   = (unsigned short*)(ws + O_QT);
    unsigned short* Kt   = (unsigned short*)(ws + O_KT);
    unsigned short* Vt   = (unsigned short*)(ws + O_VT);
    unsigned short* ao2b = xln;                              // xln dead after chunk-2 KV
    unsigned short* xn   = AO;                               // AO dead after out-proj
    unsigned short* h192 = Qt;                               // Qt dead after attention
    unsigned short* pjcat= (unsigned short*)(ws + O_QT + 2433024); // after h192
    unsigned short* catb = Kt;                               // Kt dead after attention

    float* xt            = ws + O_XT;
    unsigned short* xtn  = (unsigned short*)(ws + O_XTN);
    float* qkvt          = ws + O_QKVT;
    unsigned short* at   = (unsigned short*)(ws + O_AT);
    unsigned short* atp  = (unsigned short*)(ws + O_ATP);
    unsigned short* th   = (unsigned short*)(ws + O_TH);
    float* xt2           = ws + O_XT2;
    int*   mapq          = (int*)(ws + O_MQ);
    int*   mapkv         = (int*)(ws + O_MKV);
    float* cb            = ws + O_CB;

    // ---- weight conversion ----
    auto conv = [&](const float* s, unsigned short* dst, int n) {
        convert_k<<<(n + 255) / 256, 256, 0, stream>>>(s, dst, n);
    };
    conv(in_w, w_in, 2304 * 768);
    conv(outw, w_out, 768 * 768);
    conv(fcw,  w_fc,  3072 * 768);
    conv(t1w,  w_t1,  192 * 768);
    conv(t2w,  w_t2,  768 * 192);
    conv(s1w,  w_s1,  192 * 768);
    conv(s2w,  w_s2,  768 * 192);
    conv(m1w,  w_m1,  192 * 768);
    combine_bias_k<<<3, 256, 0, stream>>>(pjb, m2b, cb);

    // ---- temporal path ----
    gather_cls_k<<<384, 256, 0, stream>>>(x, xt);
    ln_k<unsigned short><<<32, 256, 0, stream>>>(xt, xtn, ln1g, ln1b, 128);
    gemm_mfma_k<0,0><<<dim3(36,1), 256, 0, stream>>>(xtn, nullptr, w_in, 768, in_b, 1.f, qkvt, nullptr, 2304, 768, 2304, nullptr);
    attn_temporal_k<<<dim3(16,12), 64, 0, stream>>>(qkvt, at);
    gemm_mfma_k<0,1><<<dim3(12,1), 256, 0, stream>>>(at,  nullptr, w_out, 768, outb, 1.f, nullptr, atp, 768, 768, 768, nullptr);
    gemm_mfma_k<1,1><<<dim3(3,1),  256, 0, stream>>>(atp, nullptr, w_t1,  768, t1b, 1.f, nullptr, th,  192, 768, 192, nullptr);
    gemm_mfma_k<0,0><<<dim3(12,1), 256, 0, stream>>>(th,  nullptr, w_t2,  192, t2b, 1.f, xt2, nullptr, 768, 192, 768, nullptr);

    // ---- LN1 with fused x2-gather ----
    ln_gather_k<<<6336, 256, 0, stream>>>(x, xt2, xln, ln1g, ln1b);

    // ---- QKV + attention, 2 n-chunks of 64 ----
    for (int c = 0; c < 2; ++c) {
        const int nbase = c * NSZ;
        build_maps_k<<<148, 256, 0, stream>>>(mapq, mapkv, nbase);
        gemm_mfma_k<0,5><<<dim3(12,99),  256, 0, stream>>>(xln, mapq,  w_in,              768, in_b,        1.f, nullptr, Qt, 768, 768, 768, nullptr);
        gemm_mfma_k<0,3><<<dim3(12,197), 256, 0, stream>>>(xln, mapkv, w_in + 768 * 768,  768, in_b + 768,  1.f, nullptr, Kt, 768, 768, 768, nullptr);
        gemm_mfma_k<0,3><<<dim3(12,197), 256, 0, stream>>>(xln, mapkv, w_in + 1536 * 768, 768, in_b + 1536, 1.f, nullptr, Vt, 768, 768, 768, nullptr);
        attn_mfma_k<<<dim3(7,12,64), 256, 0, stream>>>(Qt, Kt, Vt, AO, nbase);
    }

    // ---- build concat-K proj weights (Qt region free now) ----
    convert2d_k<<<9216, 256, 0, stream>>>(pjw, 768, 3072, 3072, pjcat, KCAT, 1.f);
    convert2d_k<<<576,  256, 0, stream>>>(m2w, 768, 192, 192, pjcat + 3072, KCAT, 0.5f);

    // ---- out-proj + s-adapter + fused residual/token-drop ----
    gemm_mfma_k<0,1><<<dim3(12,198), 256, 0, stream>>>(AO,   nullptr, w_out, 768, outb, 1.f, nullptr, ao2b, 768, 768, 768, nullptr);
    gemm_mfma_k<1,1><<<dim3(3,198),  256, 0, stream>>>(ao2b, nullptr, w_s1,  768, s1b,  1.f, nullptr, h192, 192, 768, 192, nullptr);
    gemm_mfma_k<0,8><<<dim3(12,198), 256, 0, stream>>>(h192, nullptr, w_s2,  192, s2b,  1.f, out, ao2b, 768, 192, 768, x);

    // ---- LN2 + M-chunked MLP with concat-K m-adapter fusion ----
    ln_k<unsigned short><<<6304, 256, 0, stream>>>(out, xn, ln2g, ln2b, R3);
    const int nbm[4] = {49, 49, 49, 50};
    int moff = 0;
    for (int mc = 0; mc < 4; ++mc) {
        const int nb = nbm[mc];
        gemm_mfma_k<2,1><<<dim3(48,nb), 256, 0, stream>>>(xn + (size_t)moff * 768, nullptr, w_fc, 768, fcb, 1.f, nullptr, catb, 3072, 768, KCAT, nullptr);
        gemm_mfma_k<1,1><<<dim3(3,nb),  256, 0, stream>>>(xn + (size_t)moff * 768, nullptr, w_m1, 768, m1b, 1.f, nullptr, catb + 3072, 192, 768, KCAT, nullptr);
        gemm_mfma_k<0,6><<<dim3(12,nb), 256, 0, stream>>>(catb, nullptr, pjcat, KCAT, cb, 1.f, out + (size_t)moff * 768, nullptr, 768, KCAT, 768, nullptr);
        moff += nb * 128;
    }
}